// Round 9
// baseline (143.490 us; speedup 1.0000x reference)
//
#include <hip/hip_runtime.h>
#include <hip/hip_bf16.h>
#include <math.h>

#define D    64
#define F3   192
#define FS   128          // stored feats channels: [sum(64) | max(64)]
#define NPB  256          // nodes per bucket (local dst = 8 bits)
#define LBITS 8
#define SBITS 17          // src id fits in 17 bits (N=100000 < 131072)
#define NBLK 256          // edge blocks for binning passes
#define SCAN_CHUNK 2048   // 256 threads * 8 elements (== 1<<11)

using bf16x8 = __attribute__((ext_vector_type(8))) short;
using u16x8  = __attribute__((ext_vector_type(8))) unsigned short;
using f32x4  = __attribute__((ext_vector_type(4))) float;

__device__ __forceinline__ ushort f2bf(float f) {
    __hip_bfloat16 h = __float2bfloat16(f);
    return *reinterpret_cast<ushort*>(&h);
}
__device__ __forceinline__ float bf2f(ushort u) {
    unsigned v = ((unsigned)u) << 16;
    return __uint_as_float(v);
}

// ---------------- Pre-cast: x and W to bf16 (one kernel) ----------------
__global__ __launch_bounds__(256) void k_cast(
    const float* __restrict__ x, ushort* __restrict__ xb, int n4,
    const float* __restrict__ W, ushort* __restrict__ Wb, int nW)
{
    if ((int)blockIdx.x < (n4 + 255) / 256) {
        int i = blockIdx.x * 256 + threadIdx.x;
        if (i < n4) {
            float4 v = *reinterpret_cast<const float4*>(x + (size_t)i * 4);
            ushort4 u = { f2bf(v.x), f2bf(v.y), f2bf(v.z), f2bf(v.w) };
            *reinterpret_cast<ushort4*>(xb + (size_t)i * 4) = u;
        }
    } else {
        for (int i = threadIdx.x; i < nW; i += 256) Wb[i] = f2bf(W[i]);
    }
}

// ---------------- Phase A: bucketed CSR construction ----------------

__global__ __launch_bounds__(256) void k_bin_hist(
    const int* __restrict__ dstv, unsigned* __restrict__ bcntT,
    int E, int EPB, int NB)
{
    __shared__ unsigned h[512];
    for (int i = threadIdx.x; i < NB; i += 256) h[i] = 0;
    __syncthreads();
    int lo = blockIdx.x * EPB, hi = min(E, lo + EPB);
    for (int e = lo + threadIdx.x; e < hi; e += 256)
        atomicAdd(&h[((unsigned)dstv[e]) >> LBITS], 1u);
    __syncthreads();
    for (int i = threadIdx.x; i < NB; i += 256)
        bcntT[(size_t)i * NBLK + blockIdx.x] = h[i];
}

__global__ __launch_bounds__(256) void k_chunk_scan(
    const unsigned* __restrict__ cnt, unsigned* __restrict__ offs,
    unsigned* __restrict__ partials, int N)
{
    __shared__ unsigned ts[256];
    int t = threadIdx.x;
    int ebase = blockIdx.x * SCAN_CHUNK + t * 8;
    unsigned v[8];
    unsigned s = 0;
    #pragma unroll
    for (int j = 0; j < 8; ++j) {
        unsigned c = (ebase + j < N) ? cnt[ebase + j] : 0u;
        v[j] = s; s += c;
    }
    ts[t] = s;
    __syncthreads();
    #pragma unroll
    for (int off = 1; off < 256; off <<= 1) {
        unsigned add = (t >= off) ? ts[t - off] : 0u;
        __syncthreads();
        ts[t] += add;
        __syncthreads();
    }
    unsigned tb = (t > 0) ? ts[t - 1] : 0u;
    #pragma unroll
    for (int j = 0; j < 8; ++j)
        if (ebase + j < N) offs[ebase + j] = tb + v[j];
    if (t == 255) partials[blockIdx.x] = ts[255];
}

__global__ void k_scan_partials(unsigned* partials, int n)
{
    if (blockIdx.x == 0 && threadIdx.x == 0) {
        unsigned s = 0;
        for (int i = 0; i < n; ++i) { unsigned c = partials[i]; partials[i] = s; s += c; }
    }
}

// cursor init folds in the chunk-partial add (no k_add_base pass).
__global__ __launch_bounds__(256) void k_bin_scatter(
    const int* __restrict__ srcv, const int* __restrict__ dstv,
    const unsigned* __restrict__ bbaseT, const unsigned* __restrict__ partials,
    unsigned* __restrict__ binned, int E, int EPB, int NB)
{
    __shared__ unsigned cur[512];
    for (int i = threadIdx.x; i < NB; i += 256) {
        unsigned idx = (unsigned)i * NBLK + blockIdx.x;
        cur[i] = bbaseT[idx] + partials[idx >> 11];
    }
    __syncthreads();
    int lo = blockIdx.x * EPB, hi = min(E, lo + EPB);
    for (int e = lo + threadIdx.x; e < hi; e += 256) {
        unsigned d = (unsigned)dstv[e];
        unsigned s = (unsigned)srcv[e];
        unsigned p = atomicAdd(&cur[d >> LBITS], 1u);
        binned[p] = ((d & (NPB - 1u)) << SBITS) | s;
    }
}

__global__ __launch_bounds__(256) void k_bucket_csr(
    const unsigned* __restrict__ binned, const unsigned* __restrict__ bbaseT,
    const unsigned* __restrict__ partials,
    unsigned* __restrict__ offs, unsigned* __restrict__ cnt,
    unsigned* __restrict__ ssrc, int E, int NB, int N)
{
    __shared__ unsigned c[256];
    __shared__ unsigned ts[256];
    int k = blockIdx.x;
    int t = threadIdx.x;
    unsigned i0 = (unsigned)k * NBLK;
    unsigned bstart = bbaseT[i0] + partials[i0 >> 11];
    unsigned bend;
    if (k + 1 < NB) {
        unsigned i1 = (unsigned)(k + 1) * NBLK;
        bend = bbaseT[i1] + partials[i1 >> 11];
    } else bend = (unsigned)E;

    c[t] = 0;
    __syncthreads();
    for (unsigned e = bstart + t; e < bend; e += 256)
        atomicAdd(&c[binned[e] >> SBITS], 1u);
    __syncthreads();

    unsigned myc = c[t];
    ts[t] = myc;
    __syncthreads();
    #pragma unroll
    for (int off = 1; off < 256; off <<= 1) {
        unsigned add = (t >= off) ? ts[t - off] : 0u;
        __syncthreads();
        ts[t] += add;
        __syncthreads();
    }
    unsigned excl = t ? ts[t - 1] : 0u;

    int gn = k * NPB + t;
    if (gn < N) { offs[gn] = bstart + excl; cnt[gn] = myc; }

    c[t] = excl;
    __syncthreads();
    for (unsigned e = bstart + t; e < bend; e += 256) {
        unsigned u  = binned[e];
        unsigned ld = u >> SBITS;
        unsigned r  = atomicAdd(&c[ld], 1u);
        ssrc[bstart + r] = u & ((1u << SBITS) - 1u);
    }
}

// ---------------- Phase B: gather, lane = channel ----------------
// Wave = node; lane owns channel `lane` of the node's sum AND max — no
// cross-lane reduction at all. Per edge: 1 broadcast ssrc load (same addr
// all lanes) + 1 global_load_ushort (64 lanes x 2B = 128B coalesced row)
// + cvt/add/max. 4-deep unroll = 4 independent row reads in flight.
__global__ __launch_bounds__(256) void k_gather3(
    const ushort*   __restrict__ xb,      // [N][64] bf16
    const unsigned* __restrict__ ssrc,
    const unsigned* __restrict__ offs,
    const unsigned* __restrict__ cnt,
    ushort*         __restrict__ feats,   // [N][128] bf16
    int N)
{
    int tid  = threadIdx.x;
    unsigned lane = tid & 63;
    int wv   = tid >> 6;

    int n = blockIdx.x * 4 + wv;
    if (n >= N) return;

    unsigned st = offs[n];
    unsigned dg = cnt[n];

    float s = 0.0f, m = -INFINITY;
    unsigned i = 0;
    for (; i + 4 <= dg; i += 4) {
        unsigned e0 = ssrc[st + i + 0];
        unsigned e1 = ssrc[st + i + 1];
        unsigned e2 = ssrc[st + i + 2];
        unsigned e3 = ssrc[st + i + 3];
        float a0 = bf2f(xb[(e0 << 6) | lane]);
        float a1 = bf2f(xb[(e1 << 6) | lane]);
        float a2 = bf2f(xb[(e2 << 6) | lane]);
        float a3 = bf2f(xb[(e3 << 6) | lane]);
        s += a0 + a1 + a2 + a3;
        m = fmaxf(fmaxf(m, fmaxf(a0, a1)), fmaxf(a2, a3));
    }
    for (; i < dg; ++i) {
        unsigned e0 = ssrc[st + i];
        float a0 = bf2f(xb[(e0 << 6) | lane]);
        s += a0;
        m = fmaxf(m, a0);
    }

    size_t fb = (size_t)n * FS;
    feats[fb + lane]      = f2bf(s);
    feats[fb + 64 + lane] = dg ? f2bf(m) : (ushort)0;
}

// ---------------- Phase C: MFMA MLP ----------------
// out[16-tile] = [sum|mean|max] @ Wb^T + b. Block = 4 waves = 4 col-blocks;
// grid = N/16 tiles. A-row = lane&15 -> mean frag = sum frag * inv (per-lane
// scalar). 6 x mfma_f32_16x16x32_bf16.
__global__ __launch_bounds__(256) void k_mlp2(
    const ushort*   __restrict__ feats,   // [N][128] bf16
    const unsigned* __restrict__ cnt,
    const ushort*   __restrict__ Wb,      // [64][192] bf16
    const float*    __restrict__ bias,    // [64]
    float*          __restrict__ out,     // [N][64]
    int N)
{
    int tid  = threadIdx.x;
    int lane = tid & 63;
    int wv   = tid >> 6;
    int l16  = lane & 15;
    int kb   = (lane >> 4) << 3;

    int col = (wv << 4) + l16;
    const ushort* wp = Wb + (size_t)col * F3 + kb;
    bf16x8 bS0 = *reinterpret_cast<const bf16x8*>(wp);
    bf16x8 bS1 = *reinterpret_cast<const bf16x8*>(wp + 32);
    bf16x8 bM0 = *reinterpret_cast<const bf16x8*>(wp + 64);
    bf16x8 bM1 = *reinterpret_cast<const bf16x8*>(wp + 96);
    bf16x8 bX0 = *reinterpret_cast<const bf16x8*>(wp + 128);
    bf16x8 bX1 = *reinterpret_cast<const bf16x8*>(wp + 160);
    float bo = bias[col];

    int n0 = blockIdx.x << 4;            // N divisible by 16

    unsigned dgr = cnt[n0 + l16];
    float inv = dgr ? 1.0f / (float)dgr : 0.0f;

    const ushort* arow = feats + (size_t)(n0 + l16) * FS + kb;
    bf16x8 aS0 = *reinterpret_cast<const bf16x8*>(arow);
    bf16x8 aS1 = *reinterpret_cast<const bf16x8*>(arow + 32);
    bf16x8 aX0 = *reinterpret_cast<const bf16x8*>(arow + 64);
    bf16x8 aX1 = *reinterpret_cast<const bf16x8*>(arow + 96);

    bf16x8 aM0, aM1;
    #pragma unroll
    for (int j = 0; j < 8; ++j) {
        aM0[j] = (short)f2bf(bf2f((ushort)aS0[j]) * inv);
        aM1[j] = (short)f2bf(bf2f((ushort)aS1[j]) * inv);
    }

    f32x4 acc = { bo, bo, bo, bo };
    acc = __builtin_amdgcn_mfma_f32_16x16x32_bf16(aS0, bS0, acc, 0, 0, 0);
    acc = __builtin_amdgcn_mfma_f32_16x16x32_bf16(aS1, bS1, acc, 0, 0, 0);
    acc = __builtin_amdgcn_mfma_f32_16x16x32_bf16(aM0, bM0, acc, 0, 0, 0);
    acc = __builtin_amdgcn_mfma_f32_16x16x32_bf16(aM1, bM1, acc, 0, 0, 0);
    acc = __builtin_amdgcn_mfma_f32_16x16x32_bf16(aX0, bX0, acc, 0, 0, 0);
    acc = __builtin_amdgcn_mfma_f32_16x16x32_bf16(aX1, bX1, acc, 0, 0, 0);

    int rbase = n0 + ((lane >> 4) << 2);
    #pragma unroll
    for (int r = 0; r < 4; ++r)
        out[(size_t)(rbase + r) * D + col] = acc[r];
}

extern "C" void kernel_launch(void* const* d_in, const int* in_sizes, int n_in,
                              void* d_out, int out_size, void* d_ws, size_t ws_size,
                              hipStream_t stream)
{
    const float* x  = (const float*)d_in[0];
    const int*   ei = (const int*)d_in[1];
    const float* W  = (const float*)d_in[2];
    const float* b  = (const float*)d_in[3];
    float* out = (float*)d_out;

    int N = in_sizes[0] / D;
    int E = in_sizes[1] / 2;
    const int* srcv = ei;
    const int* dstv = ei + E;

    int NB  = (N + NPB - 1) / NPB;          // 391 buckets
    int EPB = (E + NBLK - 1) / NBLK;
    int M   = NB * NBLK;

    unsigned* bcntT    = (unsigned*)d_ws;          // [M]
    unsigned* bbaseT   = bcntT + M;                // [M]
    unsigned* partials = bbaseT + M;               // [64]
    unsigned* offs     = partials + 64;            // [N]
    unsigned* cnt      = offs + N;                 // [N]
    unsigned* ssrc     = cnt + N;                  // [E]
    unsigned* binned   = ssrc + E;                 // [E]
    ushort*   xb       = (ushort*)(binned + E);    // [N*64] bf16
    ushort*   Wb       = xb + (size_t)N * D;       // [64*192] bf16
    ushort*   feats    = Wb + (size_t)D * F3;      // [N*128] bf16  (~50 MB total)

    int nChunksM = (M + SCAN_CHUNK - 1) / SCAN_CHUNK;
    int n4 = N * D / 4;

    k_cast<<<(n4 + 255) / 256 + 1, 256, 0, stream>>>(x, xb, n4, W, Wb, D * F3);

    k_bin_hist<<<NBLK, 256, 0, stream>>>(dstv, bcntT, E, EPB, NB);
    k_chunk_scan<<<nChunksM, 256, 0, stream>>>(bcntT, bbaseT, partials, M);
    k_scan_partials<<<1, 64, 0, stream>>>(partials, nChunksM);
    k_bin_scatter<<<NBLK, 256, 0, stream>>>(srcv, dstv, bbaseT, partials, binned, E, EPB, NB);
    k_bucket_csr<<<NB, 256, 0, stream>>>(binned, bbaseT, partials, offs, cnt, ssrc, E, NB, N);

    k_gather3<<<(N + 3) / 4, 256, 0, stream>>>(xb, ssrc, offs, cnt, feats, N);
    k_mlp2<<<N / 16, 256, 0, stream>>>(feats, cnt, Wb, b, out, N);
}

// Round 10
// 123.471 us; speedup vs baseline: 1.1621x; 1.1621x over previous
//
#include <hip/hip_runtime.h>
#include <hip/hip_bf16.h>
#include <math.h>

#define D    64
#define F3   192
#define FS   128          // stored feats channels: [sum(64) | max(64)]
#define NPB  256          // nodes per bucket (local dst = 8 bits)
#define LBITS 8
#define SBITS 17          // src id fits in 17 bits (N=100000 < 131072)
#define NBLK 256          // edge blocks for binning passes
#define SCAN_CHUNK 2048   // 256 threads * 8 elements (== 1<<11)
#define BUCKET_PAD 1800   // per-bucket ssrc slack: 256 nodes * 7 + align
#define SSRC_CAP   2000000

using bf16x8 = __attribute__((ext_vector_type(8))) short;
using f32x4  = __attribute__((ext_vector_type(4))) float;

__device__ __forceinline__ ushort f2bf(float f) {
    __hip_bfloat16 h = __float2bfloat16(f);
    return *reinterpret_cast<ushort*>(&h);
}
__device__ __forceinline__ float bf2f(ushort u) {
    unsigned v = ((unsigned)u) << 16;
    return __uint_as_float(v);
}

// ---------------- A1 + pre-cast: hist | xcast | wcast by block range -------
__global__ __launch_bounds__(256) void k_cast_hist(
    const float* __restrict__ x, ushort* __restrict__ xb, int n4,
    const float* __restrict__ W, ushort* __restrict__ Wb, int nW,
    const int* __restrict__ dstv, unsigned* __restrict__ bcntT,
    int E, int EPB, int NB, int castBlocks)
{
    int bid = blockIdx.x;
    if (bid < NBLK) {
        __shared__ unsigned h[512];
        for (int i = threadIdx.x; i < NB; i += 256) h[i] = 0;
        __syncthreads();
        int lo = bid * EPB, hi = min(E, lo + EPB);
        for (int e = lo + threadIdx.x; e < hi; e += 256)
            atomicAdd(&h[((unsigned)dstv[e]) >> LBITS], 1u);
        __syncthreads();
        for (int i = threadIdx.x; i < NB; i += 256)
            bcntT[(size_t)i * NBLK + bid] = h[i];
    } else if (bid < NBLK + castBlocks) {
        int i = (bid - NBLK) * 256 + threadIdx.x;
        if (i < n4) {
            float4 v = *reinterpret_cast<const float4*>(x + (size_t)i * 4);
            ushort4 u = { f2bf(v.x), f2bf(v.y), f2bf(v.z), f2bf(v.w) };
            *reinterpret_cast<ushort4*>(xb + (size_t)i * 4) = u;
        }
    } else {
        for (int i = threadIdx.x; i < nW; i += 256) Wb[i] = f2bf(W[i]);
    }
}

// ---------------- A2: chunked exclusive scan of the [bucket][block] matrix --
__global__ __launch_bounds__(256) void k_chunk_scan(
    const unsigned* __restrict__ cnt, unsigned* __restrict__ offs,
    unsigned* __restrict__ partials, int N)
{
    __shared__ unsigned ts[256];
    int t = threadIdx.x;
    int ebase = blockIdx.x * SCAN_CHUNK + t * 8;
    unsigned v[8];
    unsigned s = 0;
    #pragma unroll
    for (int j = 0; j < 8; ++j) {
        unsigned c = (ebase + j < N) ? cnt[ebase + j] : 0u;
        v[j] = s; s += c;
    }
    ts[t] = s;
    __syncthreads();
    #pragma unroll
    for (int off = 1; off < 256; off <<= 1) {
        unsigned add = (t >= off) ? ts[t - off] : 0u;
        __syncthreads();
        ts[t] += add;
        __syncthreads();
    }
    unsigned tb = (t > 0) ? ts[t - 1] : 0u;
    #pragma unroll
    for (int j = 0; j < 8; ++j)
        if (ebase + j < N) offs[ebase + j] = tb + v[j];
    if (t == 255) partials[blockIdx.x] = ts[255];
}

// inline exclusive scan of chunk partials (<=64 entries) into LDS
__device__ __forceinline__ void scan_partials_lds(
    const unsigned* __restrict__ partials, unsigned* psc, int n, int t)
{
    __shared__ unsigned raw[64];
    if (t < n) raw[t] = partials[t];
    __syncthreads();
    if (t == 0) {
        unsigned s = 0;
        for (int i = 0; i < n; ++i) { unsigned c = raw[i]; psc[i] = s; s += c; }
    }
    __syncthreads();
}

// ---------------- A3: scatter edges into bucket-grouped storage -------------
__global__ __launch_bounds__(256) void k_bin_scatter(
    const int* __restrict__ srcv, const int* __restrict__ dstv,
    const unsigned* __restrict__ bbaseT, const unsigned* __restrict__ partials,
    int nChunks, unsigned* __restrict__ binned, int E, int EPB, int NB)
{
    __shared__ unsigned cur[512];
    __shared__ unsigned psc[64];
    int t = threadIdx.x;
    scan_partials_lds(partials, psc, nChunks, t);
    for (int i = t; i < NB; i += 256) {
        unsigned idx = (unsigned)i * NBLK + blockIdx.x;
        cur[i] = bbaseT[idx] + psc[idx >> 11];
    }
    __syncthreads();
    int lo = blockIdx.x * EPB, hi = min(E, lo + EPB);
    for (int e = lo + t; e < hi; e += 256) {
        unsigned d = (unsigned)dstv[e];
        unsigned s = (unsigned)srcv[e];
        unsigned p = atomicAdd(&cur[d >> LBITS], 1u);
        binned[p] = ((d & (NPB - 1u)) << SBITS) | s;
    }
}

// ---------------- A4: per-bucket CSR with 8-aligned padded node segments ----
// ssrc segment for node: start multiple of 8 entries; padded length
// (cnt+7)&~7; pad slots filled with the node's last edge id (duplicate).
__global__ __launch_bounds__(256) void k_bucket_csr(
    const unsigned* __restrict__ binned, const unsigned* __restrict__ bbaseT,
    const unsigned* __restrict__ partials, int nChunks,
    unsigned* __restrict__ offs, unsigned* __restrict__ cnt,
    unsigned* __restrict__ ssrc, int E, int NB, int N)
{
    __shared__ unsigned c[256];
    __shared__ unsigned ts[256];
    __shared__ unsigned psc[64];
    int k = blockIdx.x;
    int t = threadIdx.x;
    scan_partials_lds(partials, psc, nChunks, t);

    unsigned i0 = (unsigned)k * NBLK;
    unsigned bstart = bbaseT[i0] + psc[i0 >> 11];
    unsigned bend;
    if (k + 1 < NB) {
        unsigned i1 = (unsigned)(k + 1) * NBLK;
        bend = bbaseT[i1] + psc[i1 >> 11];
    } else bend = (unsigned)E;
    unsigned bstartPad = ((bstart + 7u) & ~7u) + (unsigned)BUCKET_PAD * k;

    c[t] = 0;
    __syncthreads();
    for (unsigned e = bstart + t; e < bend; e += 256)
        atomicAdd(&c[binned[e] >> SBITS], 1u);
    __syncthreads();

    unsigned myc  = c[t];
    unsigned mycp = (myc + 7u) & ~7u;        // padded to 8
    ts[t] = mycp;
    __syncthreads();
    #pragma unroll
    for (int off = 1; off < 256; off <<= 1) {
        unsigned add = (t >= off) ? ts[t - off] : 0u;
        __syncthreads();
        ts[t] += add;
        __syncthreads();
    }
    unsigned exclp = t ? ts[t - 1] : 0u;
    unsigned stPad = bstartPad + exclp;

    int gn = k * NPB + t;
    if (gn < N) { offs[gn] = stPad; cnt[gn] = myc; }

    c[t] = exclp;          // local padded cursor
    __syncthreads();
    for (unsigned e = bstart + t; e < bend; e += 256) {
        unsigned u  = binned[e];
        unsigned ld = u >> SBITS;
        unsigned r  = atomicAdd(&c[ld], 1u);
        ssrc[bstartPad + r] = u & ((1u << SBITS) - 1u);
    }
    __syncthreads();
    // pad fill: duplicate last id (sum compensated in gather; max unaffected)
    if (myc && mycp > myc) {
        unsigned lastId = ssrc[stPad + myc - 1];
        for (unsigned j = myc; j < mycp; ++j) ssrc[stPad + j] = lastId;
    }
}

// ---------------- Phase B: gather, lane = channel, 8 rows in flight --------
// Wave = node. Branch-free inner loop: 2 aligned uint4 id loads, then 8
// independent 128B row loads. Pad duplicates removed via s -= p*last.
__global__ __launch_bounds__(256) void k_gather4(
    const ushort*   __restrict__ xb,      // [N][64] bf16
    const unsigned* __restrict__ ssrc,
    const unsigned* __restrict__ offs,
    const unsigned* __restrict__ cnt,
    ushort*         __restrict__ feats,   // [N][128] bf16
    int N)
{
    int tid  = threadIdx.x;
    unsigned lane = tid & 63;
    int wv   = tid >> 6;

    int n = blockIdx.x * 4 + wv;
    if (n >= N) return;

    unsigned st  = offs[n];
    unsigned dg  = cnt[n];
    unsigned dgp = (dg + 7u) & ~7u;

    float s = 0.0f, m = -INFINITY;
    for (unsigned i = 0; i < dgp; i += 8) {
        uint4 ia = *reinterpret_cast<const uint4*>(ssrc + st + i);
        uint4 ib = *reinterpret_cast<const uint4*>(ssrc + st + i + 4);
        float a0 = bf2f(xb[(ia.x << 6) | lane]);
        float a1 = bf2f(xb[(ia.y << 6) | lane]);
        float a2 = bf2f(xb[(ia.z << 6) | lane]);
        float a3 = bf2f(xb[(ia.w << 6) | lane]);
        float a4 = bf2f(xb[(ib.x << 6) | lane]);
        float a5 = bf2f(xb[(ib.y << 6) | lane]);
        float a6 = bf2f(xb[(ib.z << 6) | lane]);
        float a7 = bf2f(xb[(ib.w << 6) | lane]);
        s += ((a0 + a1) + (a2 + a3)) + ((a4 + a5) + (a6 + a7));
        m = fmaxf(m, fmaxf(fmaxf(fmaxf(a0, a1), fmaxf(a2, a3)),
                           fmaxf(fmaxf(a4, a5), fmaxf(a6, a7))));
    }
    unsigned p = dgp - dg;
    if (p && dg) {
        unsigned lastId = ssrc[st + dg - 1];
        float last = bf2f(xb[(lastId << 6) | lane]);
        s -= (float)p * last;
    }

    size_t fb = (size_t)n * FS;
    feats[fb + lane]      = f2bf(s);
    feats[fb + 64 + lane] = dg ? f2bf(m) : (ushort)0;
}

// ---------------- Phase C: MFMA MLP ----------------
__global__ __launch_bounds__(256) void k_mlp2(
    const ushort*   __restrict__ feats,   // [N][128] bf16
    const unsigned* __restrict__ cnt,
    const ushort*   __restrict__ Wb,      // [64][192] bf16
    const float*    __restrict__ bias,    // [64]
    float*          __restrict__ out,     // [N][64]
    int N)
{
    int tid  = threadIdx.x;
    int lane = tid & 63;
    int wv   = tid >> 6;
    int l16  = lane & 15;
    int kb   = (lane >> 4) << 3;

    int col = (wv << 4) + l16;
    const ushort* wp = Wb + (size_t)col * F3 + kb;
    bf16x8 bS0 = *reinterpret_cast<const bf16x8*>(wp);
    bf16x8 bS1 = *reinterpret_cast<const bf16x8*>(wp + 32);
    bf16x8 bM0 = *reinterpret_cast<const bf16x8*>(wp + 64);
    bf16x8 bM1 = *reinterpret_cast<const bf16x8*>(wp + 96);
    bf16x8 bX0 = *reinterpret_cast<const bf16x8*>(wp + 128);
    bf16x8 bX1 = *reinterpret_cast<const bf16x8*>(wp + 160);
    float bo = bias[col];

    int n0 = blockIdx.x << 4;            // N divisible by 16

    unsigned dgr = cnt[n0 + l16];
    float inv = dgr ? 1.0f / (float)dgr : 0.0f;

    const ushort* arow = feats + (size_t)(n0 + l16) * FS + kb;
    bf16x8 aS0 = *reinterpret_cast<const bf16x8*>(arow);
    bf16x8 aS1 = *reinterpret_cast<const bf16x8*>(arow + 32);
    bf16x8 aX0 = *reinterpret_cast<const bf16x8*>(arow + 64);
    bf16x8 aX1 = *reinterpret_cast<const bf16x8*>(arow + 96);

    bf16x8 aM0, aM1;
    #pragma unroll
    for (int j = 0; j < 8; ++j) {
        aM0[j] = (short)f2bf(bf2f((ushort)aS0[j]) * inv);
        aM1[j] = (short)f2bf(bf2f((ushort)aS1[j]) * inv);
    }

    f32x4 acc = { bo, bo, bo, bo };
    acc = __builtin_amdgcn_mfma_f32_16x16x32_bf16(aS0, bS0, acc, 0, 0, 0);
    acc = __builtin_amdgcn_mfma_f32_16x16x32_bf16(aS1, bS1, acc, 0, 0, 0);
    acc = __builtin_amdgcn_mfma_f32_16x16x32_bf16(aM0, bM0, acc, 0, 0, 0);
    acc = __builtin_amdgcn_mfma_f32_16x16x32_bf16(aM1, bM1, acc, 0, 0, 0);
    acc = __builtin_amdgcn_mfma_f32_16x16x32_bf16(aX0, bX0, acc, 0, 0, 0);
    acc = __builtin_amdgcn_mfma_f32_16x16x32_bf16(aX1, bX1, acc, 0, 0, 0);

    int rbase = n0 + ((lane >> 4) << 2);
    #pragma unroll
    for (int r = 0; r < 4; ++r)
        out[(size_t)(rbase + r) * D + col] = acc[r];
}

extern "C" void kernel_launch(void* const* d_in, const int* in_sizes, int n_in,
                              void* d_out, int out_size, void* d_ws, size_t ws_size,
                              hipStream_t stream)
{
    const float* x  = (const float*)d_in[0];
    const int*   ei = (const int*)d_in[1];
    const float* W  = (const float*)d_in[2];
    const float* b  = (const float*)d_in[3];
    float* out = (float*)d_out;

    int N = in_sizes[0] / D;
    int E = in_sizes[1] / 2;
    const int* srcv = ei;
    const int* dstv = ei + E;

    int NB  = (N + NPB - 1) / NPB;          // 391 buckets
    int EPB = (E + NBLK - 1) / NBLK;
    int M   = NB * NBLK;                    // 100096

    unsigned* bcntT    = (unsigned*)d_ws;          // [M]       400KB
    unsigned* bbaseT   = bcntT + M;                // [M]       400KB
    unsigned* partials = bbaseT + M;               // [64]
    unsigned* offs     = partials + 64;            // [N]       400KB
    unsigned* cnt      = offs + N;                 // [N]       400KB
    unsigned* ssrc     = cnt + N;                  // [SSRC_CAP] 8MB (padded)
    ushort*   xb       = (ushort*)(ssrc + SSRC_CAP);   // [N*64]  12.8MB
    ushort*   Wb       = xb + (size_t)N * D;           // [64*192]
    ushort*   feats    = Wb + (size_t)D * F3;          // [N*128] 25.6MB
    unsigned* binned   = (unsigned*)feats;             // [E] aliases feats (dead before gather)

    int nChunksM  = (M + SCAN_CHUNK - 1) / SCAN_CHUNK;  // 49
    int n4        = N * D / 4;
    int castBlocks = (n4 + 255) / 256;

    k_cast_hist<<<NBLK + castBlocks + 1, 256, 0, stream>>>(
        x, xb, n4, W, Wb, D * F3, dstv, bcntT, E, EPB, NB, castBlocks);
    k_chunk_scan<<<nChunksM, 256, 0, stream>>>(bcntT, bbaseT, partials, M);
    k_bin_scatter<<<NBLK, 256, 0, stream>>>(srcv, dstv, bbaseT, partials,
                                            nChunksM, binned, E, EPB, NB);
    k_bucket_csr<<<NB, 256, 0, stream>>>(binned, bbaseT, partials, nChunksM,
                                         offs, cnt, ssrc, E, NB, N);
    k_gather4<<<(N + 3) / 4, 256, 0, stream>>>(xb, ssrc, offs, cnt, feats, N);
    k_mlp2<<<N / 16, 256, 0, stream>>>(feats, cnt, Wb, b, out, N);
}